// Round 5
// baseline (334.466 us; speedup 1.0000x reference)
//
#include <hip/hip_runtime.h>
#include <hip/hip_fp16.h>

#define NN 100000
#define NE 3200000
#define F 64
#define NR 8
#define PAD 34                 // LDS row stride (floats) for 32-node As
#define NCB 98                 // coarse buckets = ceil(NN/1024), bucket = dst>>10
#define CAPC 36864             // capacity per coarse bucket
#define CHUNKA 4000            // edges per binA block (800 blocks)
#define NT 3125                // node tiles = NN/32 (exact: 3125*32 = 100000)
#define SLCAP 1280             // per-tile edge list capacity (mean 1024, +8 sigma)

// ---------------- init: per-coarse-bucket staging cursors -------------------
__global__ __launch_bounds__(128) void init_kernel(int* __restrict__ cursors) {
    int t = threadIdx.x;
    if (t < NCB) cursors[t] = t * CAPC;
}

// ---------------- cvt: x fp32 -> fp16 copy (halves gather bytes + L2 set) ---
__global__ __launch_bounds__(256) void cvt_kernel(
    const float* __restrict__ x, __half* __restrict__ xh)
{
    size_t base = ((size_t)blockIdx.x * 256 + threadIdx.x) * 8;  // 800K thr * 8 = 6.4M
    float4 a = *(const float4*)(x + base);
    float4 b = *(const float4*)(x + base + 4);
    __half2 h0 = __floats2half2_rn(a.x, a.y);
    __half2 h1 = __floats2half2_rn(a.z, a.w);
    __half2 h2 = __floats2half2_rn(b.x, b.y);
    __half2 h3 = __floats2half2_rn(b.z, b.w);
    uint4 o;
    o.x = *(unsigned*)&h0; o.y = *(unsigned*)&h1;
    o.z = *(unsigned*)&h2; o.w = *(unsigned*)&h3;
    *(uint4*)(xh + base) = o;
}

// ---------------- pass A: coarse-bin edges (4-copy LDS multi-split) ---------
__global__ __launch_bounds__(256) void binA_kernel(
    const int* __restrict__ esrc, const int* __restrict__ edst,
    const int* __restrict__ etyp,
    int* __restrict__ cursors, unsigned* __restrict__ stag4)
{
    __shared__ int hist[128][4];
    __shared__ int start[128];
    __shared__ int cur[128][4];
    __shared__ int gbase[NCB];
    __shared__ uint2 recs[CHUNKA];   // 32 KB

    const int t = threadIdx.x;
    const int cp = t & 3;
    const int e0 = blockIdx.x * CHUNKA;

    if (t < 128) ((int4*)hist)[t] = make_int4(0, 0, 0, 0);
    __syncthreads();

    uint2 rec[16];
#pragma unroll
    for (int j = 0; j < 16; j++) {
        int i = t + j * 256;
        if (i < CHUNKA) {
            int e = e0 + i;
            unsigned s = (unsigned)esrc[e];
            unsigned d = (unsigned)edst[e];
            unsigned r = (unsigned)etyp[e];
            rec[j] = make_uint2(s, d | (r << 17));
            atomicAdd(&hist[d >> 10][cp], 1);
        }
    }
    __syncthreads();

    int tot = 0;
    if (t < 128) {
        int4 h4 = ((int4*)hist)[t];
        tot = h4.x + h4.y + h4.z + h4.w;
        start[t] = tot;
    }
    __syncthreads();
    for (int off = 1; off < 128; off <<= 1) {
        int v = 0;
        if (t < 128 && t >= off) v = start[t - off];
        __syncthreads();
        if (t < 128) start[t] += v;
        __syncthreads();
    }
    if (t < 128) start[t] -= tot;   // inclusive -> exclusive
    __syncthreads();
    if (t < NCB) {
        int4 h4 = ((int4*)hist)[t];
        int s = start[t];
        cur[t][0] = s;
        cur[t][1] = s + h4.x;
        cur[t][2] = s + h4.x + h4.y;
        cur[t][3] = s + h4.x + h4.y + h4.z;
        gbase[t] = atomicAdd(&cursors[t], tot);
    }
    __syncthreads();

#pragma unroll
    for (int j = 0; j < 16; j++) {
        int i = t + j * 256;
        if (i < CHUNKA) {
            int b = (int)((rec[j].y & 0x1FFFFu) >> 10);
            int slot = atomicAdd(&cur[b][cp], 1);
            recs[slot] = rec[j];
        }
    }
    __syncthreads();

#pragma unroll
    for (int j = 0; j < 16; j++) {
        int i = t + j * 256;
        if (i < CHUNKA) {
            uint2 rr = recs[i];
            int b = (int)((rr.y & 0x1FFFFu) >> 10);
            unsigned d10 = rr.y & 1023u;          // low 10 bits of dst
            unsigned r   = rr.y >> 17;
            stag4[gbase[b] + (i - start[b])] = rr.x | (d10 << 17) | (r << 27);
        }
    }
}

// ---------------- pass B: fine-bin to 32-node buckets, 8 chunks/coarse ------
__global__ __launch_bounds__(256) void binB_kernel(
    const unsigned* __restrict__ stag4, const int* __restrict__ cursors,
    unsigned* __restrict__ packed4, unsigned* __restrict__ runsd)
{
    __shared__ int h[32][4];
    __shared__ int cu[32][4];
    const int b = blockIdx.x >> 3;
    const int c = blockIdx.x & 7;
    const int t = threadIdx.x;
    const int cp = t & 3;
    const int bbase = b * CAPC;
    const int n = cursors[b] - bbase;
    const int s = (int)(((long long)c * n) >> 3);
    const int e = (int)(((long long)(c + 1) * n) >> 3);
    const int base = bbase + s;
    const int cn = e - s;

    if (t < 128) ((int*)h)[t] = 0;
    __syncthreads();
    for (int i = t; i < cn; i += 256) {
        unsigned v = stag4[base + i];
        atomicAdd(&h[(v >> 22) & 31][cp], 1);   // (dstLow10 >> 5) & 31
    }
    __syncthreads();
    if (t == 0) {
        int acc = 0;
        for (int f = 0; f < 32; f++) {
            int fstart = acc;
#pragma unroll
            for (int k = 0; k < 4; k++) { cu[f][k] = acc; acc += h[f][k]; }
            runsd[(blockIdx.x << 5) + f] = ((unsigned)(base + fstart) << 10) | (unsigned)(acc - fstart);
        }
    }
    __syncthreads();
    for (int i = t; i < cn; i += 256) {
        unsigned v = stag4[base + i];
        unsigned f = (v >> 22) & 31u;
        int p = atomicAdd(&cu[f][cp], 1);
        unsigned d5  = (v >> 17) & 31u;   // dst low 5 bits
        unsigned rel = v >> 27;
        // key8 = rel*32 + (d&31) lives in bits [17..24] -> fused key = p>>17
        packed4[base + p] = (v & 0x1FFFFu) | (d5 << 17) | (rel << 22);
    }
}

// ---------------- fused: sort + fp16 gather + GEMM --------------------------
// Round-5 change: three rounds of structure changes (barriers, occupancy
// 22-34%, MLP depth, slist placement) left dur invariant at ~200-227us with
// FETCH_SIZE pinned at 360 MB / ~1.9 TB/s -- the L2-miss path on the random
// gather (3.2M edges x 256B fp32 rows vs 4MB/XCD L2) is the saturated pipe.
// Fix: gather from a one-time fp16 copy of x -- 128B/edge (2 cache lines,
// fully coalesced per instruction slot) and a 12.8MB working set that fits
// L2 ~2x better. Accumulate fp32; root term still reads fp32 x (exact).
__global__ __launch_bounds__(128, 4) void fused_kernel(
    const float* __restrict__ x,
    const __half* __restrict__ xh,
    const unsigned* __restrict__ packed4,
    const unsigned* __restrict__ runsd,
    const float* __restrict__ weight,   // [8][64][64]
    const float* __restrict__ root,     // [64][64]
    const float* __restrict__ bias,
    float* __restrict__ out)
{
    __shared__ __align__(16) float As[64][PAD];  // As[k][node], 8.7 KB
    __shared__ __align__(16) float Ws[64][64];   // current seg's W, 16 KB
    __shared__ int kstart[257];                  // run starts; [256] = total
    __shared__ int slist[SLCAP];                 // 5 KB
    __shared__ unsigned rdesc[8];
    __shared__ int wsum[2];
    int* const kcur = (int*)&As[0][0];   // overlay: dead until staging begins

    const int t = threadIdx.x;
    const int tile = blockIdx.x;
    const int lane = t & 63;
    const int wid = t >> 6;

    if (t < 8) rdesc[t] = runsd[(((tile >> 5) * 8 + t) << 5) + (tile & 31)];
    kstart[t] = 0; kstart[t + 128] = 0;
    __syncthreads();

    // ---- hist by key8 = rel*32 + dstLow5; register-cache first iteration ----
    unsigned pc[8];
#pragma unroll
    for (int c = 0; c < 8; c++) {
        unsigned d = rdesc[c];
        int rs = (int)(d >> 10), rc = (int)(d & 1023u);
        if (t < rc) {
            pc[c] = packed4[rs + t];
            atomicAdd(&kstart[pc[c] >> 17], 1);
        }
        for (int i = t + 128; i < rc; i += 128)          // rare (rc > 128)
            atomicAdd(&kstart[packed4[rs + i] >> 17], 1);
    }
    __syncthreads();

    // ---- exclusive scan of 256 counts: 2 keys/thread, wave shfl scan ----
    const int a0 = kstart[2 * t], a1 = kstart[2 * t + 1];
    int v = a0 + a1;
#pragma unroll
    for (int off = 1; off < 64; off <<= 1) {
        int u = __shfl_up(v, off);
        if (lane >= off) v += u;
    }
    if (lane == 63) wsum[wid] = v;
    __syncthreads();                       // orders kstart reads vs writes below
    const int wo = wid ? wsum[0] : 0;
    const int incl = wo + v;
    const int ebase = incl - a0 - a1;
    kstart[2 * t]     = ebase;
    kstart[2 * t + 1] = ebase + a0;
    kcur[2 * t]       = ebase;
    kcur[2 * t + 1]   = ebase + a0;
    if (t == 127) kstart[256] = incl;      // total edge count
    __syncthreads();

    // ---- scatter into per-key runs (LDS slist; packed4 from registers) ----
#pragma unroll
    for (int c = 0; c < 8; c++) {
        unsigned d = rdesc[c];
        int rs = (int)(d >> 10), rc = (int)(d & 1023u);
        if (t < rc) {
            int slot = atomicAdd(&kcur[pc[c] >> 17], 1);
            slist[slot] = (int)(pc[c] & 0x1FFFFu);
        }
        for (int i = t + 128; i < rc; i += 128) {        // rare (rc > 128)
            unsigned p = packed4[rs + i];
            int slot = atomicAdd(&kcur[p >> 17], 1);
            slist[slot] = (int)(p & 0x1FFFFu);
        }
    }
    __syncthreads();   // sort frozen; kcur (As) dead; also guards first Ws use

    // ---- per-seg: stage Ws -> gather As (wave-private) -> barrier -> GEMM --
    const int node0 = tile * 32;
    const int w16 = wid << 4;             // wave's 16-column slice of As
    const int sn  = w16 + (lane >> 2);    // As column / node within tile
    const int sq  = lane & 3;             // k-eighth selector 0..3
    const int kb  = sq << 3;              // halfs [kb,kb+8) and [32+kb,32+kb+8)
    const int tx  = lane & 15;            // fout group
    const int tyw = lane >> 4;            // node quad within wave 0..3
    const int acol = w16 + (tyw << 2);

    float acc[4][4];
#pragma unroll
    for (int i = 0; i < 4; i++)
#pragma unroll
        for (int j = 0; j < 4; j++) acc[i][j] = 0.f;

    for (int seg = 0; seg < 9; seg++) {
        const float* __restrict__ Wseg = (seg == 0) ? root : (weight + (size_t)(seg - 1) * (F * F));

        if (seg) __syncthreads();          // all waves done reading Ws(seg-1)

        // stage Wseg -> LDS: 8 coalesced float4 per thread (source L2-resident)
        {
            const float4* __restrict__ wsrc = (const float4*)Wseg;
            float4* __restrict__ wdst = (float4*)&Ws[0][0];
#pragma unroll
            for (int j = 0; j < 8; j++)
                wdst[t + (j << 7)] = wsrc[t + (j << 7)];
        }

        if (seg == 0) {
            // root: stage own-row fp32 x (transposed into As); exact
            const float* rowp = x + (size_t)(node0 + sn) * F;
            float4 v0 = *(const float4*)(rowp + kb);
            float4 v1 = *(const float4*)(rowp + kb + 4);
            float4 v2 = *(const float4*)(rowp + 32 + kb);
            float4 v3 = *(const float4*)(rowp + 32 + kb + 4);
            As[kb + 0][sn] = v0.x; As[kb + 1][sn] = v0.y;
            As[kb + 2][sn] = v0.z; As[kb + 3][sn] = v0.w;
            As[kb + 4][sn] = v1.x; As[kb + 5][sn] = v1.y;
            As[kb + 6][sn] = v1.z; As[kb + 7][sn] = v1.w;
            As[32 + kb + 0][sn] = v2.x; As[32 + kb + 1][sn] = v2.y;
            As[32 + kb + 2][sn] = v2.z; As[32 + kb + 3][sn] = v2.w;
            As[32 + kb + 4][sn] = v3.x; As[32 + kb + 5][sn] = v3.y;
            As[32 + kb + 6][sn] = v3.z; As[32 + kb + 7][sn] = v3.w;
        } else {
            // mean-gather this wave's 16 nodes for relation seg-1 (fp16 rows)
            const int key = ((seg - 1) << 5) | sn;
            const int beg = kstart[key];
            const int end = kstart[key + 1];   // prefix property: next start
            // 16 fp32 accumulators: k in [kb,kb+8) and [32+kb,32+kb+8)
            float4 A0 = make_float4(0.f, 0.f, 0.f, 0.f);
            float4 A1 = A0, B0 = A0, B1 = A0;
            int i = beg;
            // 4-edge unroll: 8 independent 16B line-loads in flight
            for (; i + 4 <= end; i += 4) {
                const __half* h0 = xh + (size_t)slist[i]     * F + kb;
                const __half* h1 = xh + (size_t)slist[i + 1] * F + kb;
                const __half* h2 = xh + (size_t)slist[i + 2] * F + kb;
                const __half* h3 = xh + (size_t)slist[i + 3] * F + kb;
                uint4 la0 = *(const uint4*)(h0);      uint4 lb0 = *(const uint4*)(h0 + 32);
                uint4 la1 = *(const uint4*)(h1);      uint4 lb1 = *(const uint4*)(h1 + 32);
                uint4 la2 = *(const uint4*)(h2);      uint4 lb2 = *(const uint4*)(h2 + 32);
                uint4 la3 = *(const uint4*)(h3);      uint4 lb3 = *(const uint4*)(h3 + 32);
#define ACC8(v, P, Q) { \
                float2 t0 = __half22float2(*(const __half2*)&(v).x); \
                float2 t1 = __half22float2(*(const __half2*)&(v).y); \
                float2 t2 = __half22float2(*(const __half2*)&(v).z); \
                float2 t3 = __half22float2(*(const __half2*)&(v).w); \
                P.x += t0.x; P.y += t0.y; P.z += t1.x; P.w += t1.y; \
                Q.x += t2.x; Q.y += t2.y; Q.z += t3.x; Q.w += t3.y; }
                ACC8(la0, A0, A1) ACC8(la1, A0, A1) ACC8(la2, A0, A1) ACC8(la3, A0, A1)
                ACC8(lb0, B0, B1) ACC8(lb1, B0, B1) ACC8(lb2, B0, B1) ACC8(lb3, B0, B1)
            }
            for (; i < end; i++) {
                const __half* h0 = xh + (size_t)slist[i] * F + kb;
                uint4 la = *(const uint4*)(h0);
                uint4 lb = *(const uint4*)(h0 + 32);
                ACC8(la, A0, A1)
                ACC8(lb, B0, B1)
            }
#undef ACC8
            const float scl = 1.0f / (float)max(end - beg, 1);
            As[kb + 0][sn] = A0.x * scl; As[kb + 1][sn] = A0.y * scl;
            As[kb + 2][sn] = A0.z * scl; As[kb + 3][sn] = A0.w * scl;
            As[kb + 4][sn] = A1.x * scl; As[kb + 5][sn] = A1.y * scl;
            As[kb + 6][sn] = A1.z * scl; As[kb + 7][sn] = A1.w * scl;
            As[32 + kb + 0][sn] = B0.x * scl; As[32 + kb + 1][sn] = B0.y * scl;
            As[32 + kb + 2][sn] = B0.z * scl; As[32 + kb + 3][sn] = B0.w * scl;
            As[32 + kb + 4][sn] = B1.x * scl; As[32 + kb + 5][sn] = B1.y * scl;
            As[32 + kb + 6][sn] = B1.z * scl; As[32 + kb + 7][sn] = B1.w * scl;
        }
        __syncthreads();                   // Ws(seg) + As staged & visible

        // GEMM: a from LDS (own 16 cols), b from LDS Ws -- all lgkmcnt,
        // no vmem in the inner loop.
#pragma unroll 8
        for (int k = 0; k < 64; k++) {
            float4 a = *(const float4*)&As[k][acol];
            float4 b = *(const float4*)&Ws[k][tx << 2];
            acc[0][0] = fmaf(a.x, b.x, acc[0][0]);
            acc[0][1] = fmaf(a.x, b.y, acc[0][1]);
            acc[0][2] = fmaf(a.x, b.z, acc[0][2]);
            acc[0][3] = fmaf(a.x, b.w, acc[0][3]);
            acc[1][0] = fmaf(a.y, b.x, acc[1][0]);
            acc[1][1] = fmaf(a.y, b.y, acc[1][1]);
            acc[1][2] = fmaf(a.y, b.z, acc[1][2]);
            acc[1][3] = fmaf(a.y, b.w, acc[1][3]);
            acc[2][0] = fmaf(a.z, b.x, acc[2][0]);
            acc[2][1] = fmaf(a.z, b.y, acc[2][1]);
            acc[2][2] = fmaf(a.z, b.z, acc[2][2]);
            acc[2][3] = fmaf(a.z, b.w, acc[2][3]);
            acc[3][0] = fmaf(a.w, b.x, acc[3][0]);
            acc[3][1] = fmaf(a.w, b.y, acc[3][1]);
            acc[3][2] = fmaf(a.w, b.z, acc[3][2]);
            acc[3][3] = fmaf(a.w, b.w, acc[3][3]);
        }
    }

    // epilogue: + bias, coalesced float4 stores
    float4 bv = *(const float4*)(bias + (tx << 2));
#pragma unroll
    for (int i = 0; i < 4; i++) {
        int node = node0 + w16 + (tyw << 2) + i;   // always < NN (NN%32==0)
        float4 o = make_float4(acc[i][0] + bv.x, acc[i][1] + bv.y,
                               acc[i][2] + bv.z, acc[i][3] + bv.w);
        *(float4*)(out + (size_t)node * F + (tx << 2)) = o;
    }
}

extern "C" void kernel_launch(void* const* d_in, const int* in_sizes, int n_in,
                              void* d_out, int out_size, void* d_ws, size_t ws_size,
                              hipStream_t stream) {
    const float* x    = (const float*)d_in[0];
    const int*   ei   = (const int*)d_in[1];
    const int*   et   = (const int*)d_in[2];
    const float* wgt  = (const float*)d_in[3];
    const float* root = (const float*)d_in[4];
    const float* bias = (const float*)d_in[5];
    float*       out  = (float*)d_out;

    int*      cursors = (int*)d_ws;                                   // [128]
    unsigned* runsd   = (unsigned*)((char*)d_ws + 512);               // [784*32]
    unsigned* stag4   = (unsigned*)((char*)d_ws + 512 + 100352);      // 14.5 MB
    unsigned* packed4 = stag4 + (size_t)NCB * CAPC;                   // 14.5 MB
    __half*   xh      = (__half*)(packed4 + (size_t)NCB * CAPC);      // 12.8 MB

    init_kernel<<<1, 128, 0, stream>>>(cursors);
    cvt_kernel<<<NN * F / (256 * 8), 256, 0, stream>>>(x, xh);
    binA_kernel<<<NE / CHUNKA, 256, 0, stream>>>(ei, ei + NE, et, cursors, stag4);
    binB_kernel<<<NCB * 8, 256, 0, stream>>>(stag4, cursors, packed4, runsd);
    fused_kernel<<<NT, 128, 0, stream>>>(x, xh, packed4, runsd, wgt, root, bias, out);
}

// Round 6
// 232.943 us; speedup vs baseline: 1.4358x; 1.4358x over previous
//
#include <hip/hip_runtime.h>
#include <hip/hip_fp16.h>

#define NN 100000
#define NE 3200000
#define F 64
#define NR 8
#define NCB 98                 // coarse buckets = ceil(NN/1024), bucket = dst>>10
#define CAPC 36864             // capacity per coarse bucket
#define CHUNKA 4000            // edges per binA block (800 blocks)
#define NT 3125                // node tiles = NN/32 (exact: 3125*32 = 100000)
#define SLCAP 1280             // per-tile edge list capacity (mean 1024, +8 sigma)

typedef _Float16 half8 __attribute__((ext_vector_type(8)));
typedef float f32x4 __attribute__((ext_vector_type(4)));
union U4H8 { uint4 u; half8 h; };

// ---------------- init: per-coarse-bucket staging cursors -------------------
__global__ __launch_bounds__(128) void init_kernel(int* __restrict__ cursors) {
    int t = threadIdx.x;
    if (t < NCB) cursors[t] = t * CAPC;
}

// ---------------- cvt: x fp32 -> fp16 copy ----------------------------------
__global__ __launch_bounds__(256) void cvt_kernel(
    const float* __restrict__ x, __half* __restrict__ xh)
{
    size_t base = ((size_t)blockIdx.x * 256 + threadIdx.x) * 8;
    float4 a = *(const float4*)(x + base);
    float4 b = *(const float4*)(x + base + 4);
    __half2 h0 = __floats2half2_rn(a.x, a.y);
    __half2 h1 = __floats2half2_rn(a.z, a.w);
    __half2 h2 = __floats2half2_rn(b.x, b.y);
    __half2 h3 = __floats2half2_rn(b.z, b.w);
    uint4 o;
    o.x = *(unsigned*)&h0; o.y = *(unsigned*)&h1;
    o.z = *(unsigned*)&h2; o.w = *(unsigned*)&h3;
    *(uint4*)(xh + base) = o;
}

// ---------------- cvtw: {root, weight} -> fp16 TRANSPOSED wt9[s][n][k] ------
__global__ __launch_bounds__(256) void cvtw_kernel(
    const float* __restrict__ weight, const float* __restrict__ root,
    __half* __restrict__ wt9)
{
    int gid = blockIdx.x * 256 + threadIdx.x;   // 0..36863
    int s = gid >> 12;
    int rem = gid & 4095;
    int k = rem >> 6, n = rem & 63;
    const float* src = (s == 0) ? root : (weight + ((size_t)(s - 1) << 12));
    wt9[((size_t)s << 12) + (n << 6) + k] = __float2half_rn(src[(k << 6) + n]);
}

// ---------------- pass A: coarse-bin edges (4-copy LDS multi-split) ---------
__global__ __launch_bounds__(256) void binA_kernel(
    const int* __restrict__ esrc, const int* __restrict__ edst,
    const int* __restrict__ etyp,
    int* __restrict__ cursors, unsigned* __restrict__ stag4)
{
    __shared__ int hist[128][4];
    __shared__ int start[128];
    __shared__ int cur[128][4];
    __shared__ int gbase[NCB];
    __shared__ uint2 recs[CHUNKA];   // 32 KB

    const int t = threadIdx.x;
    const int cp = t & 3;
    const int e0 = blockIdx.x * CHUNKA;

    if (t < 128) ((int4*)hist)[t] = make_int4(0, 0, 0, 0);
    __syncthreads();

    uint2 rec[16];
#pragma unroll
    for (int j = 0; j < 16; j++) {
        int i = t + j * 256;
        if (i < CHUNKA) {
            int e = e0 + i;
            unsigned s = (unsigned)esrc[e];
            unsigned d = (unsigned)edst[e];
            unsigned r = (unsigned)etyp[e];
            rec[j] = make_uint2(s, d | (r << 17));
            atomicAdd(&hist[d >> 10][cp], 1);
        }
    }
    __syncthreads();

    int tot = 0;
    if (t < 128) {
        int4 h4 = ((int4*)hist)[t];
        tot = h4.x + h4.y + h4.z + h4.w;
        start[t] = tot;
    }
    __syncthreads();
    for (int off = 1; off < 128; off <<= 1) {
        int v = 0;
        if (t < 128 && t >= off) v = start[t - off];
        __syncthreads();
        if (t < 128) start[t] += v;
        __syncthreads();
    }
    if (t < 128) start[t] -= tot;   // inclusive -> exclusive
    __syncthreads();
    if (t < NCB) {
        int4 h4 = ((int4*)hist)[t];
        int s = start[t];
        cur[t][0] = s;
        cur[t][1] = s + h4.x;
        cur[t][2] = s + h4.x + h4.y;
        cur[t][3] = s + h4.x + h4.y + h4.z;
        gbase[t] = atomicAdd(&cursors[t], tot);
    }
    __syncthreads();

#pragma unroll
    for (int j = 0; j < 16; j++) {
        int i = t + j * 256;
        if (i < CHUNKA) {
            int b = (int)((rec[j].y & 0x1FFFFu) >> 10);
            int slot = atomicAdd(&cur[b][cp], 1);
            recs[slot] = rec[j];
        }
    }
    __syncthreads();

#pragma unroll
    for (int j = 0; j < 16; j++) {
        int i = t + j * 256;
        if (i < CHUNKA) {
            uint2 rr = recs[i];
            int b = (int)((rr.y & 0x1FFFFu) >> 10);
            unsigned d10 = rr.y & 1023u;          // low 10 bits of dst
            unsigned r   = rr.y >> 17;
            stag4[gbase[b] + (i - start[b])] = rr.x | (d10 << 17) | (r << 27);
        }
    }
}

// ---------------- pass B: fine-bin to 32-node buckets, 8 chunks/coarse ------
__global__ __launch_bounds__(256) void binB_kernel(
    const unsigned* __restrict__ stag4, const int* __restrict__ cursors,
    unsigned* __restrict__ packed4, unsigned* __restrict__ runsd)
{
    __shared__ int h[32][4];
    __shared__ int cu[32][4];
    const int b = blockIdx.x >> 3;
    const int c = blockIdx.x & 7;
    const int t = threadIdx.x;
    const int cp = t & 3;
    const int bbase = b * CAPC;
    const int n = cursors[b] - bbase;
    const int s = (int)(((long long)c * n) >> 3);
    const int e = (int)(((long long)(c + 1) * n) >> 3);
    const int base = bbase + s;
    const int cn = e - s;

    if (t < 128) ((int*)h)[t] = 0;
    __syncthreads();
    for (int i = t; i < cn; i += 256) {
        unsigned v = stag4[base + i];
        atomicAdd(&h[(v >> 22) & 31][cp], 1);   // (dstLow10 >> 5) & 31
    }
    __syncthreads();
    if (t == 0) {
        int acc = 0;
        for (int f = 0; f < 32; f++) {
            int fstart = acc;
#pragma unroll
            for (int k = 0; k < 4; k++) { cu[f][k] = acc; acc += h[f][k]; }
            runsd[(blockIdx.x << 5) + f] = ((unsigned)(base + fstart) << 10) | (unsigned)(acc - fstart);
        }
    }
    __syncthreads();
    for (int i = t; i < cn; i += 256) {
        unsigned v = stag4[base + i];
        unsigned f = (v >> 22) & 31u;
        int p = atomicAdd(&cu[f][cp], 1);
        unsigned d5  = (v >> 17) & 31u;   // dst low 5 bits
        unsigned rel = v >> 27;
        // key8 = rel*32 + (d&31) lives in bits [17..24] -> fused key = p>>17
        packed4[base + p] = (v & 0x1FFFFu) | (d5 << 17) | (rel << 22);
    }
}

// ---------------- fused: sort + fp16 gather + MFMA GEMM ---------------------
// Round-6 change: fetch bytes halved with ZERO time change (R5) -> fused is
// not memory-bound; the invariant consumer is the fp32 vector-FMA GEMM
// (9216 VALU inst/thread = ~112K issue cycles/SIMD vs 500K wall). Replace it
// with v_mfma_f32_16x16x32_f16: per wave-seg 8 MFMA instead of 1024 FMA.
// A = As[32 nodes][64 k] fp16 (XOR-swizzled, same wave-private gather, now
// packed fp16); B = pre-transposed fp16 wt9[seg][fout][k] staged to LDS.
// A/B use identical k->position maps (permutation-safe); C/D mapping is the
// doc-verified col=lane&15,row=(lane>>4)*4+reg. LDS 31.7 -> 18.5 KB.
__global__ __launch_bounds__(128, 4) void fused_kernel(
    const __half* __restrict__ xh,
    const unsigned* __restrict__ packed4,
    const unsigned* __restrict__ runsd,
    const __half* __restrict__ wt9,     // [9][64 fout][64 k] fp16 (0 = root)
    const float* __restrict__ bias,
    float* __restrict__ out)
{
    __shared__ __align__(16) char Asb[32 * 128];   // As[node][k] fp16, swizzled, 4 KB
    __shared__ __align__(16) char Wtb[64 * 128];   // Wt[fout][k] fp16, swizzled, 8 KB
    __shared__ int kstart[257];                    // run starts; [256] = total
    __shared__ int slist[SLCAP];                   // 5 KB
    __shared__ unsigned rdesc[8];
    __shared__ int wsum[2];
    int* const kcur = (int*)Asb;         // overlay: dead until staging begins

    const int t = threadIdx.x;
    const int tile = blockIdx.x;
    const int lane = t & 63;
    const int wid = t >> 6;

    if (t < 8) rdesc[t] = runsd[(((tile >> 5) * 8 + t) << 5) + (tile & 31)];
    kstart[t] = 0; kstart[t + 128] = 0;
    __syncthreads();

    // ---- hist by key8 = rel*32 + dstLow5; register-cache first iteration ----
    unsigned pc[8];
#pragma unroll
    for (int c = 0; c < 8; c++) {
        unsigned d = rdesc[c];
        int rs = (int)(d >> 10), rc = (int)(d & 1023u);
        if (t < rc) {
            pc[c] = packed4[rs + t];
            atomicAdd(&kstart[pc[c] >> 17], 1);
        }
        for (int i = t + 128; i < rc; i += 128)          // rare (rc > 128)
            atomicAdd(&kstart[packed4[rs + i] >> 17], 1);
    }
    __syncthreads();

    // ---- exclusive scan of 256 counts: 2 keys/thread, wave shfl scan ----
    const int a0 = kstart[2 * t], a1 = kstart[2 * t + 1];
    int v = a0 + a1;
#pragma unroll
    for (int off = 1; off < 64; off <<= 1) {
        int u = __shfl_up(v, off);
        if (lane >= off) v += u;
    }
    if (lane == 63) wsum[wid] = v;
    __syncthreads();                       // orders kstart reads vs writes below
    const int wo = wid ? wsum[0] : 0;
    const int incl = wo + v;
    const int ebase = incl - a0 - a1;
    kstart[2 * t]     = ebase;
    kstart[2 * t + 1] = ebase + a0;
    kcur[2 * t]       = ebase;
    kcur[2 * t + 1]   = ebase + a0;
    if (t == 127) kstart[256] = incl;      // total edge count
    __syncthreads();

    // ---- scatter into per-key runs (LDS slist; packed4 from registers) ----
#pragma unroll
    for (int c = 0; c < 8; c++) {
        unsigned d = rdesc[c];
        int rs = (int)(d >> 10), rc = (int)(d & 1023u);
        if (t < rc) {
            int slot = atomicAdd(&kcur[pc[c] >> 17], 1);
            slist[slot] = (int)(pc[c] & 0x1FFFFu);
        }
        for (int i = t + 128; i < rc; i += 128) {        // rare (rc > 128)
            unsigned p = packed4[rs + i];
            int slot = atomicAdd(&kcur[p >> 17], 1);
            slist[slot] = (int)(p & 0x1FFFFu);
        }
    }
    __syncthreads();   // sort frozen; kcur (Asb) dead

    // ---- per-seg: stage Wt -> gather As (wave-private fp16) -> MFMA --------
    const int node0 = tile * 32;
    const int w16 = wid << 4;             // wave's 16-node slice
    const int sn  = w16 + (lane >> 2);    // gather: node within tile 0..31
    const int sq  = lane & 3;             // gather: k-eighth 0..3
    const int kb  = sq << 3;              // halfs [kb,kb+8) and [32+kb,...)
    const unsigned snswz = (unsigned)((sn & 7) << 4);
    char* const awp = Asb + sn * 128;

    // MFMA fragment indices
    const int ml = lane & 15;             // 16-dim: node (A) / fout (B,D)
    const int kg = lane >> 4;             // k-group 0..3
    const int arow = w16 + ml;            // A row = node within tile
    const unsigned aswz = (unsigned)((arow & 7) << 4);
    const unsigned kb0 = (unsigned)(kg << 4);   // kbyte within 64B k-half

    f32x4 acc[4];
#pragma unroll
    for (int nt = 0; nt < 4; nt++)
#pragma unroll
        for (int i = 0; i < 4; i++) acc[nt][i] = 0.f;

    for (int seg = 0; seg < 9; seg++) {
        if (seg) __syncthreads();          // all waves done reading Wtb(seg-1)

        // stage Wt(seg) -> LDS with XOR swizzle (coalesced fp16 source)
        {
            const uint4* __restrict__ wsrc = (const uint4*)(wt9 + ((size_t)seg << 12));
#pragma unroll
            for (int j = 0; j < 4; j++) {
                int c = t + (j << 7);                       // 0..511
                int n = c >> 3;
                unsigned kbyt = (unsigned)((c & 7) << 4);
                *(uint4*)(Wtb + n * 128 + (kbyt ^ (unsigned)((n & 7) << 4))) = wsrc[c];
            }
        }

        if (seg == 0) {
            // root: copy own-row xh straight into As (fp16, swizzled)
            const __half* rowp = xh + (size_t)(node0 + sn) * F + kb;
            uint4 va = *(const uint4*)(rowp);
            uint4 vb = *(const uint4*)(rowp + 32);
            *(uint4*)(awp + (((unsigned)(sq << 4)) ^ snswz)) = va;
            *(uint4*)(awp + ((64u | (unsigned)(sq << 4)) ^ snswz)) = vb;
        } else {
            // mean-gather this wave's 16 nodes for relation seg-1 (fp16 rows)
            const int key = ((seg - 1) << 5) | sn;
            const int beg = kstart[key];
            const int end = kstart[key + 1];   // prefix property: next start
            float4 A0 = make_float4(0.f, 0.f, 0.f, 0.f);
            float4 A1 = A0, B0 = A0, B1 = A0;
            int i = beg;
            for (; i + 4 <= end; i += 4) {     // 4-edge unroll
                const __half* h0 = xh + (size_t)slist[i]     * F + kb;
                const __half* h1 = xh + (size_t)slist[i + 1] * F + kb;
                const __half* h2 = xh + (size_t)slist[i + 2] * F + kb;
                const __half* h3 = xh + (size_t)slist[i + 3] * F + kb;
                uint4 la0 = *(const uint4*)(h0);      uint4 lb0 = *(const uint4*)(h0 + 32);
                uint4 la1 = *(const uint4*)(h1);      uint4 lb1 = *(const uint4*)(h1 + 32);
                uint4 la2 = *(const uint4*)(h2);      uint4 lb2 = *(const uint4*)(h2 + 32);
                uint4 la3 = *(const uint4*)(h3);      uint4 lb3 = *(const uint4*)(h3 + 32);
#define ACC8(v, P, Q) { \
                float2 t0 = __half22float2(*(const __half2*)&(v).x); \
                float2 t1 = __half22float2(*(const __half2*)&(v).y); \
                float2 t2 = __half22float2(*(const __half2*)&(v).z); \
                float2 t3 = __half22float2(*(const __half2*)&(v).w); \
                P.x += t0.x; P.y += t0.y; P.z += t1.x; P.w += t1.y; \
                Q.x += t2.x; Q.y += t2.y; Q.z += t3.x; Q.w += t3.y; }
                ACC8(la0, A0, A1) ACC8(la1, A0, A1) ACC8(la2, A0, A1) ACC8(la3, A0, A1)
                ACC8(lb0, B0, B1) ACC8(lb1, B0, B1) ACC8(lb2, B0, B1) ACC8(lb3, B0, B1)
            }
            for (; i < end; i++) {
                const __half* h0 = xh + (size_t)slist[i] * F + kb;
                uint4 la = *(const uint4*)(h0);
                uint4 lb = *(const uint4*)(h0 + 32);
                ACC8(la, A0, A1)
                ACC8(lb, B0, B1)
            }
#undef ACC8
            const float scl = 1.0f / (float)max(end - beg, 1);
            __half2 p0 = __floats2half2_rn(A0.x * scl, A0.y * scl);
            __half2 p1 = __floats2half2_rn(A0.z * scl, A0.w * scl);
            __half2 p2 = __floats2half2_rn(A1.x * scl, A1.y * scl);
            __half2 p3 = __floats2half2_rn(A1.z * scl, A1.w * scl);
            __half2 q0 = __floats2half2_rn(B0.x * scl, B0.y * scl);
            __half2 q1 = __floats2half2_rn(B0.z * scl, B0.w * scl);
            __half2 q2 = __floats2half2_rn(B1.x * scl, B1.y * scl);
            __half2 q3 = __floats2half2_rn(B1.z * scl, B1.w * scl);
            uint4 pa, pb;
            pa.x = *(unsigned*)&p0; pa.y = *(unsigned*)&p1;
            pa.z = *(unsigned*)&p2; pa.w = *(unsigned*)&p3;
            pb.x = *(unsigned*)&q0; pb.y = *(unsigned*)&q1;
            pb.z = *(unsigned*)&q2; pb.w = *(unsigned*)&q3;
            *(uint4*)(awp + (((unsigned)(sq << 4)) ^ snswz)) = pa;
            *(uint4*)(awp + ((64u | (unsigned)(sq << 4)) ^ snswz)) = pb;
        }
        __syncthreads();                   // Wtb(seg) staged & visible

        // MFMA GEMM: D[16 node x 64 fout] += A[16x64] * W[64x64]
        U4H8 fa0, fa1;
        fa0.u = *(const uint4*)(Asb + arow * 128 + (kb0 ^ aswz));
        fa1.u = *(const uint4*)(Asb + arow * 128 + ((64u | kb0) ^ aswz));
#pragma unroll
        for (int nt = 0; nt < 4; nt++) {
            int wrow = (nt << 4) + ml;
            unsigned wswz = (unsigned)((wrow & 7) << 4);
            U4H8 fb0, fb1;
            fb0.u = *(const uint4*)(Wtb + wrow * 128 + (kb0 ^ wswz));
            fb1.u = *(const uint4*)(Wtb + wrow * 128 + ((64u | kb0) ^ wswz));
            acc[nt] = __builtin_amdgcn_mfma_f32_16x16x32_f16(fa0.h, fb0.h, acc[nt], 0, 0, 0);
            acc[nt] = __builtin_amdgcn_mfma_f32_16x16x32_f16(fa1.h, fb1.h, acc[nt], 0, 0, 0);
        }
    }

    // epilogue: + bias; D mapping col=lane&15, row=(lane>>4)*4+i (verified)
#pragma unroll
    for (int nt = 0; nt < 4; nt++) {
        float bb = bias[(nt << 4) + ml];
#pragma unroll
        for (int i = 0; i < 4; i++) {
            int node = node0 + w16 + (kg << 2) + i;
            out[(size_t)node * F + (nt << 4) + ml] = acc[nt][i] + bb;
        }
    }
}

extern "C" void kernel_launch(void* const* d_in, const int* in_sizes, int n_in,
                              void* d_out, int out_size, void* d_ws, size_t ws_size,
                              hipStream_t stream) {
    const float* x    = (const float*)d_in[0];
    const int*   ei   = (const int*)d_in[1];
    const int*   et   = (const int*)d_in[2];
    const float* wgt  = (const float*)d_in[3];
    const float* root = (const float*)d_in[4];
    const float* bias = (const float*)d_in[5];
    float*       out  = (float*)d_out;

    int*      cursors = (int*)d_ws;                                   // [128]
    unsigned* runsd   = (unsigned*)((char*)d_ws + 512);               // [784*32]
    unsigned* stag4   = (unsigned*)((char*)d_ws + 512 + 100352);      // 14.5 MB
    unsigned* packed4 = stag4 + (size_t)NCB * CAPC;                   // 14.5 MB
    __half*   xh      = (__half*)(packed4 + (size_t)NCB * CAPC);      // 12.8 MB
    __half*   wt9     = xh + (size_t)NN * F;                          // 72 KB

    init_kernel<<<1, 128, 0, stream>>>(cursors);
    cvt_kernel<<<NN * F / (256 * 8), 256, 0, stream>>>(x, xh);
    cvtw_kernel<<<144, 256, 0, stream>>>(wgt, root, wt9);
    binA_kernel<<<NE / CHUNKA, 256, 0, stream>>>(ei, ei + NE, et, cursors, stag4);
    binB_kernel<<<NCB * 8, 256, 0, stream>>>(stag4, cursors, packed4, runsd);
    fused_kernel<<<NT, 128, 0, stream>>>(xh, packed4, runsd, wt9, bias, out);
}